// Round 8
// baseline (177.213 us; speedup 1.0000x reference)
//
#include <hip/hip_runtime.h>
#include <hip/hip_bf16.h>

// Problem constants
#define NE 384      // n_embed
#define HD 64       // head dim
#define TT 8        // block (sequence) length
#define NBATCH 32768

typedef __bf16 bf16;
typedef bf16 bf16x8 __attribute__((ext_vector_type(8)));
typedef bf16 bf16x4 __attribute__((ext_vector_type(4)));
typedef float f32x4 __attribute__((ext_vector_type(4)));

// k-slot permutation sigma(lg, j): lane-group lg holds k = {4lg..4lg+3} and
// {16+4lg..16+4lg+3}. Makes each x-load instruction's 4 lg-lanes contiguous
// (full 64-B sectors). A and B use the same sigma -> dot product unchanged.
__device__ __host__ inline int sigma_k(int lg, int j) {
    return (j < 4) ? (lg * 4 + j) : (16 + lg * 4 + (j - 4));
}

// ---------------------------------------------------------------------------
// Kernel 0: convert Wq|Wk|Wv (each [384,64] f32, row-major, y = x@W) into a
// bf16 fragment table in MFMA B-fragment order (with sigma k-mapping):
//   wt[((kk*12 + n)*64 + lane)*8 + j] = W_all[kk*32 + sigma(lane>>4, j)][col]
//   col = n*16 + (lane&15).  Table = 144 KB -> L2-resident on every XCD.
// ---------------------------------------------------------------------------
__global__ void prep_wt(const float* __restrict__ Wq, const float* __restrict__ Wk,
                        const float* __restrict__ Wv, bf16* __restrict__ wt) {
    int c = blockIdx.x * blockDim.x + threadIdx.x;   // chunk id: one lane-slot (8 elems)
    if (c >= 12 * 12 * 64) return;
    int kk   = c / (12 * 64);
    int rem  = c % (12 * 64);
    int n    = rem / 64;
    int lane = rem % 64;
    int col  = n * 16 + (lane & 15);
    int lg   = lane >> 4;
    const float* src; int cc;
    if (col < 64)       { src = Wq; cc = col; }
    else if (col < 128) { src = Wk; cc = col - 64; }
    else                { src = Wv; cc = col - 128; }
    bf16* dst = wt + (size_t)c * 8;
    #pragma unroll
    for (int j = 0; j < 8; ++j) {
        int k = kk * 32 + sigma_k(lg, j);
        dst[j] = (bf16)src[(size_t)k * 64 + cc];
    }
}

// ---------------------------------------------------------------------------
// Kernel 1: fused qkv projection + causal attention — ZERO barriers, NO LDS
// weight table, MAX stagger. Grid: 2048 blocks x 256 threads (4 waves).
// __launch_bounds__(256,3) -> 3 blocks/CU (LDS 44 KB) = 12 independent waves
// per CU at arbitrary phases: HBM read issue never pauses chip-wide.
// B fragments stream from the L2-resident wt table per K-step in 3 groups
// of 4 (short VGPR live ranges; no double-buffer — the r5 mistake).
// ---------------------------------------------------------------------------
template<bool PREP>
__global__ __launch_bounds__(256, 3)
void fused_head(const float* __restrict__ x, const bf16* __restrict__ wt,
                const float* __restrict__ Wq, const float* __restrict__ Wk,
                const float* __restrict__ Wv, float* __restrict__ out) {
    constexpr int STQ = 72;  // q2/k2 row stride (elems): 144 B (16B-aligned, 2-way banks)
    constexpr int STV = 40;  // vT/wei row stride (elems): 80 B (16B-aligned, 2-way banks)
    constexpr int WSZ = 2 * 16 * STQ + 64 * STV + 16 * STV;  // 5504 elems = 11008 B/wave
    __shared__ __align__(16) bf16 smem[4][WSZ];              // 44032 B/block

    const int tid  = threadIdx.x;
    const int wid  = tid >> 6;
    const int lane = tid & 63;
    const int lr   = lane & 15;   // fragment row / col index
    const int lg   = lane >> 4;   // k-group

    bf16* q2  = smem[wid];                 // [16][STQ] row-major, cols 0..63 = q
    bf16* k2  = q2 + 16 * STQ;             // [16][STQ] row-major, cols 0..63 = k
    bf16* vT  = k2 + 16 * STQ;             // [64][STV]: vT[h][s] = v[s][h]; s 16..31 zero
    bf16* wei = vT + 64 * STV;             // [16][STV]: P block; cols 16..31 zero

    // zero the K=32 padding regions (cols 16..31) — wave-private, no barrier
    {
        unsigned int* z = (unsigned int*)(vT + lane * STV + 16);
        #pragma unroll
        for (int j = 0; j < 8; ++j) z[j] = 0u;
        if (lane < 16) {
            unsigned int* zw = (unsigned int*)(wei + lane * STV + 16);
            #pragma unroll
            for (int j = 0; j < 8; ++j) zw[j] = 0u;
        }
    }

    const int wg   = blockIdx.x * 4 + wid;   // global wave id
    const int row0 = wg * 32;                // first x-row (32 rows = 4 batches)

    f32x4 acc[2][12];
    #pragma unroll
    for (int m = 0; m < 2; ++m)
        #pragma unroll
        for (int n = 0; n < 12; ++n) acc[m][n] = f32x4{0.f, 0.f, 0.f, 0.f};

    // sigma addressing: lo inst reads floats [kk*32 + lg*4, +4), hi inst +16.
    const float* xb0 = x + (size_t)(row0 + lr) * NE + lg * 4;
    const float* xb1 = xb0 + (size_t)16 * NE;

    // A prefetch ring: 2 K-steps in flight (static indexing via full unroll)
    f32x4 ab[2][4];
    #pragma unroll
    for (int s = 0; s < 2; ++s) {
        const float* p0 = xb0 + s * 32;
        const float* p1 = xb1 + s * 32;
        ab[s][0] = *(const f32x4*)(p0);
        ab[s][1] = *(const f32x4*)(p0 + 16);
        ab[s][2] = *(const f32x4*)(p1);
        ab[s][3] = *(const f32x4*)(p1 + 16);
    }

    if (PREP) {
        #pragma unroll
        for (int kk = 0; kk < 12; ++kk) {
            const int cur = kk & 1;
            bf16x8 a0, a1;
            #pragma unroll
            for (int j = 0; j < 4; ++j) {
                a0[j]     = (bf16)ab[cur][0][j];
                a0[j + 4] = (bf16)ab[cur][1][j];
                a1[j]     = (bf16)ab[cur][2][j];
                a1[j + 4] = (bf16)ab[cur][3][j];
            }
            if (kk + 2 < 12) {   // refill the A-slot just consumed (2 ahead)
                const float* p0 = xb0 + (kk + 2) * 32;
                const float* p1 = xb1 + (kk + 2) * 32;
                ab[cur][0] = *(const f32x4*)(p0);
                ab[cur][1] = *(const f32x4*)(p0 + 16);
                ab[cur][2] = *(const f32x4*)(p1);
                ab[cur][3] = *(const f32x4*)(p1 + 16);
            }
            // B straight from L2-resident wt, 3 groups of 4 fragments:
            // short live ranges keep total regs ~160 (3 waves/SIMD).
            const bf16x8* bp = (const bf16x8*)wt + (size_t)(kk * 12) * 64 + lane;
            #pragma unroll
            for (int g = 0; g < 3; ++g) {
                bf16x8 b0 = bp[(g * 4 + 0) * 64];
                bf16x8 b1 = bp[(g * 4 + 1) * 64];
                bf16x8 b2 = bp[(g * 4 + 2) * 64];
                bf16x8 b3 = bp[(g * 4 + 3) * 64];
                acc[0][g*4+0] = __builtin_amdgcn_mfma_f32_16x16x32_bf16(a0, b0, acc[0][g*4+0], 0, 0, 0);
                acc[1][g*4+0] = __builtin_amdgcn_mfma_f32_16x16x32_bf16(a1, b0, acc[1][g*4+0], 0, 0, 0);
                acc[0][g*4+1] = __builtin_amdgcn_mfma_f32_16x16x32_bf16(a0, b1, acc[0][g*4+1], 0, 0, 0);
                acc[1][g*4+1] = __builtin_amdgcn_mfma_f32_16x16x32_bf16(a1, b1, acc[1][g*4+1], 0, 0, 0);
                acc[0][g*4+2] = __builtin_amdgcn_mfma_f32_16x16x32_bf16(a0, b2, acc[0][g*4+2], 0, 0, 0);
                acc[1][g*4+2] = __builtin_amdgcn_mfma_f32_16x16x32_bf16(a1, b2, acc[1][g*4+2], 0, 0, 0);
                acc[0][g*4+3] = __builtin_amdgcn_mfma_f32_16x16x32_bf16(a0, b3, acc[0][g*4+3], 0, 0, 0);
                acc[1][g*4+3] = __builtin_amdgcn_mfma_f32_16x16x32_bf16(a1, b3, acc[1][g*4+3], 0, 0, 0);
            }
        }
    } else {  // fallback: gather weights fp32 from global (slow, ws too small)
        #pragma unroll
        for (int kk = 0; kk < 12; ++kk) {
            const int cur = kk & 1;
            bf16x8 a0, a1;
            #pragma unroll
            for (int j = 0; j < 4; ++j) {
                a0[j]     = (bf16)ab[cur][0][j];
                a0[j + 4] = (bf16)ab[cur][1][j];
                a1[j]     = (bf16)ab[cur][2][j];
                a1[j + 4] = (bf16)ab[cur][3][j];
            }
            if (kk + 2 < 12) {
                const float* p0 = xb0 + (kk + 2) * 32;
                const float* p1 = xb1 + (kk + 2) * 32;
                ab[cur][0] = *(const f32x4*)(p0);
                ab[cur][1] = *(const f32x4*)(p0 + 16);
                ab[cur][2] = *(const f32x4*)(p1);
                ab[cur][3] = *(const f32x4*)(p1 + 16);
            }
            #pragma unroll
            for (int n = 0; n < 12; ++n) {
                int col = n * 16 + lr;
                const float* ws = (col < 64) ? (Wq + col)
                                 : (col < 128) ? (Wk + (col - 64))
                                               : (Wv + (col - 128));
                bf16x8 b;
                #pragma unroll
                for (int j = 0; j < 8; ++j)
                    b[j] = (bf16)ws[(size_t)(kk * 32 + sigma_k(lg, j)) * 64];
                acc[0][n] = __builtin_amdgcn_mfma_f32_16x16x32_bf16(a0, b, acc[0][n], 0, 0, 0);
                acc[1][n] = __builtin_amdgcn_mfma_f32_16x16x32_bf16(a1, b, acc[1][n], 0, 0, 0);
            }
        }
    }

    // ---- attention per batch-pair (16 rows = 2 batches) --------------------
    const float qk_scale = 0.051031036307982884f;  // 384^-0.5 (faithful to reference)
    const f32x4 zero4 = {0.f, 0.f, 0.f, 0.f};

    #pragma unroll     // MUST fully unroll: acc[p] with runtime p would spill to scratch
    for (int p = 0; p < 2; ++p) {
        // Stage qkv from C-layout accs (lane: col = lr, rows = 4*lg + r).
        #pragma unroll
        for (int nt = 0; nt < 4; ++nt) {
            #pragma unroll
            for (int r = 0; r < 4; ++r) {
                q2[(4 * lg + r) * STQ + nt * 16 + lr] = (bf16)acc[p][nt][r];
                k2[(4 * lg + r) * STQ + nt * 16 + lr] = (bf16)acc[p][4 + nt][r];
            }
            bf16x4 vv;
            vv[0] = (bf16)acc[p][8 + nt][0];
            vv[1] = (bf16)acc[p][8 + nt][1];
            vv[2] = (bf16)acc[p][8 + nt][2];
            vv[3] = (bf16)acc[p][8 + nt][3];
            *(bf16x4*)(vT + (nt * 16 + lr) * STV + lg * 4) = vv;  // transposed V
        }

        // QK^T on the stacked 16x16 two-batch block (K = 64 -> 2 MFMAs)
        f32x4 w4 = zero4;
        #pragma unroll
        for (int kh = 0; kh < 2; ++kh) {
            bf16x8 qa = *(const bf16x8*)(q2 + lr * STQ + kh * 32 + lg * 8);
            bf16x8 kb = *(const bf16x8*)(k2 + lr * STQ + kh * 32 + lg * 8);
            w4 = __builtin_amdgcn_mfma_f32_16x16x32_bf16(qa, kb, w4, 0, 0, 0);
        }

        // mask + softmax. lane holds col s' = lr, rows t' = 4*lg + r.
        const int sb = lr >> 3;    // key batch-half
        const int s  = lr & 7;     // key index within batch
        #pragma unroll
        for (int r = 0; r < 4; ++r) {
            int tp = 4 * lg + r;
            bool valid = ((tp >> 3) == sb) && (s <= (tp & 7));  // same batch & causal
            float val = valid ? w4[r] * qk_scale : -1e30f;
            float mx = val;
            mx = fmaxf(mx, __shfl_xor(mx, 1));
            mx = fmaxf(mx, __shfl_xor(mx, 2));
            mx = fmaxf(mx, __shfl_xor(mx, 4));
            float e = valid ? __expf(val - mx) : 0.f;
            float sm = e;
            sm += __shfl_xor(sm, 1);
            sm += __shfl_xor(sm, 2);
            sm += __shfl_xor(sm, 4);
            float pn = valid ? e / sm : 0.f;   // cross-batch quadrants -> exact 0
            wei[tp * STV + lr] = (bf16)pn;
        }

        // P @ V with K=32 (upper 16 k-slots are the pre-zeroed padding)
        bf16x8 pa = *(const bf16x8*)(wei + lr * STV + lg * 8);
        const int bb2 = wg * 4 + p * 2;
        #pragma unroll
        for (int nt = 0; nt < 4; ++nt) {
            bf16x8 vb = *(const bf16x8*)(vT + (nt * 16 + lr) * STV + lg * 8);
            f32x4 o = __builtin_amdgcn_mfma_f32_16x16x32_bf16(pa, vb, zero4, 0, 0, 0);
            #pragma unroll
            for (int r = 0; r < 4; ++r) {
                int tp = 4 * lg + r;
                out[((size_t)(bb2 + (tp >> 3)) * TT + (tp & 7)) * HD + nt * 16 + lr] = o[r];
            }
        }
    }
}

// ---------------------------------------------------------------------------
extern "C" void kernel_launch(void* const* d_in, const int* in_sizes, int n_in,
                              void* d_out, int out_size, void* d_ws, size_t ws_size,
                              hipStream_t stream) {
    const float* x  = (const float*)d_in[0];
    const float* Wq = (const float*)d_in[1];
    const float* Wk = (const float*)d_in[2];
    const float* Wv = (const float*)d_in[3];
    float* out = (float*)d_out;

    const size_t wt_bytes = (size_t)12 * 12 * 64 * 8 * sizeof(bf16);  // 147456
    const int grid = NBATCH / 16;   // 2048 blocks, 4 waves x 4 batches each

    if (ws_size >= wt_bytes) {
        bf16* wt = (bf16*)d_ws;
        prep_wt<<<36, 256, 0, stream>>>(Wq, Wk, Wv, wt);
        fused_head<true><<<grid, 256, 0, stream>>>(x, wt, nullptr, nullptr, nullptr, out);
    } else {
        fused_head<false><<<grid, 256, 0, stream>>>(x, nullptr, Wq, Wk, Wv, out);
    }
}

// Round 10
// 176.834 us; speedup vs baseline: 1.0021x; 1.0021x over previous
//
#include <hip/hip_runtime.h>
#include <hip/hip_bf16.h>

// Problem constants
#define NE 384      // n_embed
#define HD 64       // head dim
#define TT 8        // block (sequence) length
#define NBATCH 32768

typedef __bf16 bf16;
typedef bf16 bf16x8 __attribute__((ext_vector_type(8)));
typedef bf16 bf16x4 __attribute__((ext_vector_type(4)));
typedef float f32x4 __attribute__((ext_vector_type(4)));

// async global->LDS, 16B per lane, dest = wave-uniform LDS base + lane*16
#define GLOAD_LDS16(g, l) __builtin_amdgcn_global_load_lds(                    \
    (const __attribute__((address_space(1))) void*)(g),                        \
    (__attribute__((address_space(3))) void*)(l), 16, 0, 0)

// ---------------------------------------------------------------------------
// Kernel 0: convert Wq|Wk|Wv (each [384,64] f32, row-major, y = x@W) into a
// bf16 fragment table in MFMA B-fragment order (standard k-map):
//   wt[((kk*12 + n)*64 + lane)*8 + j] = W_all[kk*32 + (lane>>4)*8 + j][col]
//   col = n*16 + (lane&15)
// ---------------------------------------------------------------------------
__global__ void prep_wt(const float* __restrict__ Wq, const float* __restrict__ Wk,
                        const float* __restrict__ Wv, bf16* __restrict__ wt) {
    int c = blockIdx.x * blockDim.x + threadIdx.x;
    if (c >= 12 * 12 * 64) return;
    int kk   = c / (12 * 64);
    int rem  = c % (12 * 64);
    int n    = rem / 64;
    int lane = rem % 64;
    int col  = n * 16 + (lane & 15);
    const float* src; int cc;
    if (col < 64)       { src = Wq; cc = col; }
    else if (col < 128) { src = Wk; cc = col - 64; }
    else                { src = Wv; cc = col - 128; }
    int k0 = kk * 32 + (lane >> 4) * 8;
    bf16* dst = wt + (size_t)c * 8;
    #pragma unroll
    for (int j = 0; j < 8; ++j)
        dst[j] = (bf16)src[(size_t)(k0 + j) * 64 + cc];
}

// ---------------------------------------------------------------------------
// Helpers for the persistent kernel
// ---------------------------------------------------------------------------
__device__ __forceinline__ void stage_half(const f32x4 (&ld)[24], bf16* aw, int lane) {
    // lane's 24 contiguous 16-B pieces of the 24-KB half-tile -> bf16 LDS tile
    // [16 rows][392] (384 cols + 8 pad). Each 16-B piece is within one row.
    #pragma unroll
    for (int i = 0; i < 24; ++i) {
        int ofs = i * 1024 + lane * 16;       // byte offset in half-tile
        int row = ofs / 1536;                 // 0..15
        int c16 = (ofs % 1536) >> 4;          // 0..95 (4-float unit)
        bf16x4 o;
        o[0] = (bf16)ld[i][0]; o[1] = (bf16)ld[i][1];
        o[2] = (bf16)ld[i][2]; o[3] = (bf16)ld[i][3];
        *(bf16x4*)(aw + row * 392 + c16 * 4) = o;   // 8-B aligned store
    }
}

// ---------------------------------------------------------------------------
// Kernel 1: PERSISTENT fused qkv projection + causal attention.
// Grid: 256 blocks x 256 threads (4 waves), 1 block/CU, 1 wave/SIMD.
// Each wave owns 256 contiguous x-rows (32 batches) over 8 rounds.
// Per round: stage two contiguous 24-KB half-tiles (regs->bf16 LDS),
// K-loop from LDS (B table: 9 steps in LDS, 3 from L2 wt), then the
// verified attention, whose scratch overlays the dead A-region.
// HBM reads are issued ahead at every point -> no idle windows; per-wave
// loads are long sequential bursts -> DRAM page friendly.
// ---------------------------------------------------------------------------
__global__ __launch_bounds__(256, 1)
void fused_persist(const float* __restrict__ x, const bf16* __restrict__ wt,
                   float* __restrict__ out) {
    constexpr int TSTEPS = 9;                 // B K-steps resident in LDS
    constexpr int AST = 392;                  // A-tile row stride (bf16 elems)
    constexpr int AWELEMS = 16 * AST;         // 6272 elems = 12544 B per wave
    constexpr int STQ = 72;                   // attn q2/k2 row stride
    constexpr int STV = 40;                   // attn vT/wei row stride
    // 9*12*512 table elems + 4 wave A-regions = 80384 elems = 160768 B
    __shared__ __align__(16) bf16 smem[TSTEPS * 12 * 512 + 4 * AWELEMS];

    const int tid  = threadIdx.x;
    const int wid  = tid >> 6;
    const int lane = tid & 63;
    const int lr   = lane & 15;
    const int lg   = lane >> 4;

    bf16* wtab = smem;
    bf16* aw   = smem + TSTEPS * 12 * 512 + wid * AWELEMS;

    const int w = blockIdx.x * 4 + wid;            // global wave id 0..1023
    const float* xw = x + (size_t)w * 256 * NE;    // wave's 256-row span

    // prologue: issue round-0 half-0 loads (contiguous 24 KB burst)
    f32x4 ldh[24], lda[24];
    #pragma unroll
    for (int i = 0; i < 24; ++i)
        ldh[i] = *(const f32x4*)(xw + i * 256 + lane * 4);

    // stage the 9-step B table into LDS (108 chunks of 1 KB; 27 per wave)
    #pragma unroll
    for (int r = 0; r < 27; ++r) {
        int c = wid * 27 + r;
        GLOAD_LDS16(wt + ((size_t)c * 64 + lane) * 8, smem + c * 512);
    }
    __syncthreads();   // the only barrier in the kernel

    const float qk_scale = 0.051031036307982884f;  // 384^-0.5
    const f32x4 zero4 = {0.f, 0.f, 0.f, 0.f};

    bf16* q2  = aw;                    // [16][STQ] (overlay; GEMM A-tile dead)
    bf16* k2  = q2 + 16 * STQ;
    bf16* vT  = k2 + 16 * STQ;         // [64][STV]
    bf16* wei = vT + 64 * STV;         // [16][STV]

    #pragma unroll 1
    for (int t = 0; t < 8; ++t) {
        const float* xt = xw + (size_t)t * 32 * NE;

        f32x4 acc[2][12];
        #pragma unroll
        for (int m = 0; m < 2; ++m)
            #pragma unroll
            for (int n = 0; n < 12; ++n) acc[m][n] = zero4;

        // issue half-1 loads (in flight during half-0 stage+GEMM)
        #pragma unroll
        for (int i = 0; i < 24; ++i)
            lda[i] = *(const f32x4*)(xt + 16 * NE + i * 256 + lane * 4);

        // ---- half 0: stage + GEMM into acc[0] ------------------------------
        stage_half(ldh, aw, lane);
        #pragma unroll
        for (int kk = 0; kk < 12; ++kk) {
            bf16x8 a = *(const bf16x8*)(aw + lr * AST + kk * 32 + lg * 8);
            if (kk < TSTEPS) {
                const bf16* base = wtab + (kk * 12) * 512 + lane * 8;
                #pragma unroll
                for (int n = 0; n < 12; ++n) {
                    bf16x8 b = *(const bf16x8*)(base + n * 512);
                    acc[0][n] = __builtin_amdgcn_mfma_f32_16x16x32_bf16(a, b, acc[0][n], 0, 0, 0);
                }
            } else {
                const bf16* base = wt + (size_t)(kk * 12) * 512 + lane * 8;
                #pragma unroll
                for (int n = 0; n < 12; ++n) {
                    bf16x8 b = *(const bf16x8*)(base + n * 512);
                    acc[0][n] = __builtin_amdgcn_mfma_f32_16x16x32_bf16(a, b, acc[0][n], 0, 0, 0);
                }
            }
        }

        // issue next round's half-0 loads (keeps HBM busy through attention)
        if (t < 7) {
            const float* xn = xw + (size_t)(t + 1) * 32 * NE;
            #pragma unroll
            for (int i = 0; i < 24; ++i)
                ldh[i] = *(const f32x4*)(xn + i * 256 + lane * 4);
        }

        // ---- half 1: stage + GEMM into acc[1] ------------------------------
        stage_half(lda, aw, lane);
        #pragma unroll
        for (int kk = 0; kk < 12; ++kk) {
            bf16x8 a = *(const bf16x8*)(aw + lr * AST + kk * 32 + lg * 8);
            if (kk < TSTEPS) {
                const bf16* base = wtab + (kk * 12) * 512 + lane * 8;
                #pragma unroll
                for (int n = 0; n < 12; ++n) {
                    bf16x8 b = *(const bf16x8*)(base + n * 512);
                    acc[1][n] = __builtin_amdgcn_mfma_f32_16x16x32_bf16(a, b, acc[1][n], 0, 0, 0);
                }
            } else {
                const bf16* base = wt + (size_t)(kk * 12) * 512 + lane * 8;
                #pragma unroll
                for (int n = 0; n < 12; ++n) {
                    bf16x8 b = *(const bf16x8*)(base + n * 512);
                    acc[1][n] = __builtin_amdgcn_mfma_f32_16x16x32_bf16(a, b, acc[1][n], 0, 0, 0);
                }
            }
        }

        // ---- attention (verified r6 code; scratch overlays dead A-tile) ----
        {
            unsigned int* z = (unsigned int*)(vT + lane * STV + 16);
            #pragma unroll
            for (int j = 0; j < 8; ++j) z[j] = 0u;
            if (lane < 16) {
                unsigned int* zw = (unsigned int*)(wei + lane * STV + 16);
                #pragma unroll
                for (int j = 0; j < 8; ++j) zw[j] = 0u;
            }
        }

        #pragma unroll
        for (int p = 0; p < 2; ++p) {
            #pragma unroll
            for (int nt = 0; nt < 4; ++nt) {
                #pragma unroll
                for (int r = 0; r < 4; ++r) {
                    q2[(4 * lg + r) * STQ + nt * 16 + lr] = (bf16)acc[p][nt][r];
                    k2[(4 * lg + r) * STQ + nt * 16 + lr] = (bf16)acc[p][4 + nt][r];
                }
                bf16x4 vv;
                vv[0] = (bf16)acc[p][8 + nt][0];
                vv[1] = (bf16)acc[p][8 + nt][1];
                vv[2] = (bf16)acc[p][8 + nt][2];
                vv[3] = (bf16)acc[p][8 + nt][3];
                *(bf16x4*)(vT + (nt * 16 + lr) * STV + lg * 4) = vv;
            }

            f32x4 w4 = zero4;
            #pragma unroll
            for (int kh = 0; kh < 2; ++kh) {
                bf16x8 qa = *(const bf16x8*)(q2 + lr * STQ + kh * 32 + lg * 8);
                bf16x8 kb = *(const bf16x8*)(k2 + lr * STQ + kh * 32 + lg * 8);
                w4 = __builtin_amdgcn_mfma_f32_16x16x32_bf16(qa, kb, w4, 0, 0, 0);
            }

            const int sb = lr >> 3;
            const int s  = lr & 7;
            #pragma unroll
            for (int r = 0; r < 4; ++r) {
                int tp = 4 * lg + r;
                bool valid = ((tp >> 3) == sb) && (s <= (tp & 7));
                float val = valid ? w4[r] * qk_scale : -1e30f;
                float mx = val;
                mx = fmaxf(mx, __shfl_xor(mx, 1));
                mx = fmaxf(mx, __shfl_xor(mx, 2));
                mx = fmaxf(mx, __shfl_xor(mx, 4));
                float e = valid ? __expf(val - mx) : 0.f;
                float sm = e;
                sm += __shfl_xor(sm, 1);
                sm += __shfl_xor(sm, 2);
                sm += __shfl_xor(sm, 4);
                float pn = valid ? e / sm : 0.f;
                wei[tp * STV + lr] = (bf16)pn;
            }

            bf16x8 pa = *(const bf16x8*)(wei + lr * STV + lg * 8);
            const int bb2 = w * 32 + t * 4 + p * 2;
            #pragma unroll
            for (int nt = 0; nt < 4; ++nt) {
                bf16x8 vb = *(const bf16x8*)(vT + (nt * 16 + lr) * STV + lg * 8);
                f32x4 o = __builtin_amdgcn_mfma_f32_16x16x32_bf16(pa, vb, zero4, 0, 0, 0);
                #pragma unroll
                for (int r = 0; r < 4; ++r) {
                    int tp = 4 * lg + r;
                    out[((size_t)(bb2 + (tp >> 3)) * TT + (tp & 7)) * HD + nt * 16 + lr] = o[r];
                }
            }
        }
    }
}

// ---------------------------------------------------------------------------
// Fallback (ws too small): barrier-free kernel, B gathered from global
// weights. Correctness-only path; never taken in practice.
// ---------------------------------------------------------------------------
__global__ __launch_bounds__(256, 2)
void fused_fallback(const float* __restrict__ x, const float* __restrict__ Wq,
                    const float* __restrict__ Wk, const float* __restrict__ Wv,
                    float* __restrict__ out) {
    constexpr int STQ = 72;
    constexpr int STV = 40;
    constexpr int WSZ = 2 * 16 * STQ + 64 * STV + 16 * STV;
    __shared__ __align__(16) bf16 smem[4][WSZ];

    const int tid  = threadIdx.x;
    const int wid  = tid >> 6;
    const int lane = tid & 63;
    const int lr   = lane & 15;
    const int lg   = lane >> 4;

    bf16* q2  = smem[wid];
    bf16* k2  = q2 + 16 * STQ;
    bf16* vT  = k2 + 16 * STQ;
    bf16* wei = vT + 64 * STV;

    {
        unsigned int* z = (unsigned int*)(vT + lane * STV + 16);
        #pragma unroll
        for (int j = 0; j < 8; ++j) z[j] = 0u;
        if (lane < 16) {
            unsigned int* zw = (unsigned int*)(wei + lane * STV + 16);
            #pragma unroll
            for (int j = 0; j < 8; ++j) zw[j] = 0u;
        }
    }

    const int wg   = blockIdx.x * 4 + wid;
    const int row0 = wg * 32;

    f32x4 acc[2][12];
    #pragma unroll
    for (int m = 0; m < 2; ++m)
        #pragma unroll
        for (int n = 0; n < 12; ++n) acc[m][n] = f32x4{0.f, 0.f, 0.f, 0.f};

    const float* xb0 = x + (size_t)(row0 + lr) * NE + lg * 8;
    const float* xb1 = xb0 + (size_t)16 * NE;

    for (int kk = 0; kk < 12; ++kk) {
        bf16x8 a0, a1;
        f32x4 c0lo = *(const f32x4*)(xb0 + kk * 32);
        f32x4 c0hi = *(const f32x4*)(xb0 + kk * 32 + 4);
        f32x4 c1lo = *(const f32x4*)(xb1 + kk * 32);
        f32x4 c1hi = *(const f32x4*)(xb1 + kk * 32 + 4);
        #pragma unroll
        for (int j = 0; j < 4; ++j) {
            a0[j] = (bf16)c0lo[j]; a0[j + 4] = (bf16)c0hi[j];
            a1[j] = (bf16)c1lo[j]; a1[j + 4] = (bf16)c1hi[j];
        }
        #pragma unroll
        for (int n = 0; n < 12; ++n) {
            int col = n * 16 + lr;
            const float* ws = (col < 64) ? (Wq + col)
                             : (col < 128) ? (Wk + (col - 64))
                                           : (Wv + (col - 128));
            bf16x8 b;
            #pragma unroll
            for (int j = 0; j < 8; ++j)
                b[j] = (bf16)ws[(size_t)(kk * 32 + lg * 8 + j) * 64];
            acc[0][n] = __builtin_amdgcn_mfma_f32_16x16x32_bf16(a0, b, acc[0][n], 0, 0, 0);
            acc[1][n] = __builtin_amdgcn_mfma_f32_16x16x32_bf16(a1, b, acc[1][n], 0, 0, 0);
        }
    }

    const float qk_scale = 0.051031036307982884f;
    const f32x4 zero4 = {0.f, 0.f, 0.f, 0.f};

    #pragma unroll
    for (int p = 0; p < 2; ++p) {
        #pragma unroll
        for (int nt = 0; nt < 4; ++nt) {
            #pragma unroll
            for (int r = 0; r < 4; ++r) {
                q2[(4 * lg + r) * STQ + nt * 16 + lr] = (bf16)acc[p][nt][r];
                k2[(4 * lg + r) * STQ + nt * 16 + lr] = (bf16)acc[p][4 + nt][r];
            }
            bf16x4 vv;
            vv[0] = (bf16)acc[p][8 + nt][0];
            vv[1] = (bf16)acc[p][8 + nt][1];
            vv[2] = (bf16)acc[p][8 + nt][2];
            vv[3] = (bf16)acc[p][8 + nt][3];
            *(bf16x4*)(vT + (nt * 16 + lr) * STV + lg * 4) = vv;
        }
        f32x4 w4 = zero4;
        #pragma unroll
        for (int kh = 0; kh < 2; ++kh) {
            bf16x8 qa = *(const bf16x8*)(q2 + lr * STQ + kh * 32 + lg * 8);
            bf16x8 kb = *(const bf16x8*)(k2 + lr * STQ + kh * 32 + lg * 8);
            w4 = __builtin_amdgcn_mfma_f32_16x16x32_bf16(qa, kb, w4, 0, 0, 0);
        }
        const int sb = lr >> 3;
        const int s  = lr & 7;
        #pragma unroll
        for (int r = 0; r < 4; ++r) {
            int tp = 4 * lg + r;
            bool valid = ((tp >> 3) == sb) && (s <= (tp & 7));
            float val = valid ? w4[r] * qk_scale : -1e30f;
            float mx = val;
            mx = fmaxf(mx, __shfl_xor(mx, 1));
            mx = fmaxf(mx, __shfl_xor(mx, 2));
            mx = fmaxf(mx, __shfl_xor(mx, 4));
            float e = valid ? __expf(val - mx) : 0.f;
            float sm = e;
            sm += __shfl_xor(sm, 1);
            sm += __shfl_xor(sm, 2);
            sm += __shfl_xor(sm, 4);
            float pn = valid ? e / sm : 0.f;
            wei[tp * STV + lr] = (bf16)pn;
        }
        bf16x8 pa = *(const bf16x8*)(wei + lr * STV + lg * 8);
        const int bb2 = wg * 4 + p * 2;
        #pragma unroll
        for (int nt = 0; nt < 4; ++nt) {
            bf16x8 vb = *(const bf16x8*)(vT + (nt * 16 + lr) * STV + lg * 8);
            f32x4 o = __builtin_amdgcn_mfma_f32_16x16x32_bf16(pa, vb, zero4, 0, 0, 0);
            #pragma unroll
            for (int r = 0; r < 4; ++r) {
                int tp = 4 * lg + r;
                out[((size_t)(bb2 + (tp >> 3)) * TT + (tp & 7)) * HD + nt * 16 + lr] = o[r];
            }
        }
    }
}

// ---------------------------------------------------------------------------
extern "C" void kernel_launch(void* const* d_in, const int* in_sizes, int n_in,
                              void* d_out, int out_size, void* d_ws, size_t ws_size,
                              hipStream_t stream) {
    const float* x  = (const float*)d_in[0];
    const float* Wq = (const float*)d_in[1];
    const float* Wk = (const float*)d_in[2];
    const float* Wv = (const float*)d_in[3];
    float* out = (float*)d_out;

    const size_t wt_bytes = (size_t)12 * 12 * 64 * 8 * sizeof(bf16);  // 147456

    if (ws_size >= wt_bytes) {
        bf16* wt = (bf16*)d_ws;
        prep_wt<<<36, 256, 0, stream>>>(Wq, Wk, Wv, wt);
        fused_persist<<<256, 256, 0, stream>>>(x, wt, out);
    } else {
        fused_fallback<<<NBATCH / 16, 256, 0, stream>>>(x, Wq, Wk, Wv, out);
    }
}